// Round 13
// baseline (96.920 us; speedup 1.0000x reference)
//
#include <hip/hip_runtime.h>
#include <math.h>

#define B_   8
#define N_   512
#define F_   64
#define G_   64
#define M_   4
#define E_   4
#define MEG  1024

typedef __attribute__((ext_vector_type(8))) __bf16 bf16x8;
typedef __attribute__((ext_vector_type(4))) float f32x4;
typedef unsigned short ush;

static __device__ __forceinline__ ush bfu(float x) { __bf16 h = (__bf16)x; return __builtin_bit_cast(ush, h); }
static __device__ __forceinline__ bf16x8 asbf(int4 v) { return __builtin_bit_cast(bf16x8, v); }
static __device__ __forceinline__ bf16x8 cvt8(float4 a, float4 b) {
  bf16x8 r;
  r[0] = (__bf16)a.x; r[1] = (__bf16)a.y; r[2] = (__bf16)a.z; r[3] = (__bf16)a.w;
  r[4] = (__bf16)b.x; r[5] = (__bf16)b.y; r[6] = (__bf16)b.z; r[7] = (__bf16)b.w;
  return r;
}

// ---------------- K1 (self-staged): MFMA Wh -> WhF fragment-major + s1/E2 + A->bitmask ------
__global__ void __launch_bounds__(256) k1_wh(const float* __restrict__ X, const float* __restrict__ Ws,
                                             const float* __restrict__ a1, const float* __restrict__ a2,
                                             const int* __restrict__ A,
                                             ush* __restrict__ WhF, float* __restrict__ s1,
                                             float2* __restrict__ E2, unsigned* __restrict__ Amask) {
  const int tid = threadIdx.x, lane = tid & 63, w = tid >> 6, c = lane & 15, grp = lane >> 4;
  const int blk = blockIdx.x, nt = blk & 7, em = (blk >> 3) & 15, b = blk >> 7;
  const int n0 = nt * 64, bem = b * 16 + em;

  __shared__ __align__(16) ush xl[2][4][64][8];   // [kk][t][lane][i]  8KB  (X fragments)
  __shared__ __align__(16) ush wl[2][4][64][8];   // [kk][w][lane][i]  8KB  (WsT fragments)
  __shared__ float c1b[64], c2b[64];
  __shared__ __align__(16) ush st[4096];          // WhF store staging 8KB

  // A -> bitmask: one 32-bit word per thread; 128B contiguous read.
  {
    const int w2 = blk * 256 + tid;               // [be][i][cword]
    const int* ap = A + (w2 >> 4) * 512 + (w2 & 15) * 32;
    unsigned bits = 0;
#pragma unroll
    for (int kq = 0; kq < 32; kq += 4) {
      int4 v = *(const int4*)(ap + kq);
      bits |= (v.x > 0 ? 1u : 0u) << kq;
      bits |= (v.y > 0 ? 1u : 0u) << (kq + 1);
      bits |= (v.z > 0 ? 1u : 0u) << (kq + 2);
      bits |= (v.w > 0 ? 1u : 0u) << (kq + 3);
    }
    Amask[w2] = bits;
  }

  // stage X rows [n0, n0+64) -> fragment-major bf16
  {
    const int row = tid >> 2, cg = tid & 3;
    const int t = row >> 4, cc = row & 15;
    const float* xp = X + (b * 512 + n0 + row) * 64 + cg * 16;
#pragma unroll
    for (int q4 = 0; q4 < 4; ++q4) {
      float4 v = ((const float4*)xp)[q4];
      float vals[4] = {v.x, v.y, v.z, v.w};
#pragma unroll
      for (int u = 0; u < 4; ++u) {
        const int f = cg * 16 + q4 * 4 + u;
        xl[f >> 5][t][((f >> 3) & 3) * 16 + cc][f & 7] = bfu(vals[u]);
      }
    }
  }
  // stage Ws[em] transposed fragment-major + c1/c2 partial dots
  {
    const int f = tid >> 2, gq = tid & 3;
    const int kk = f >> 5, gg = (f >> 3) & 3, ii = f & 7;
    const float* wp = Ws + em * 4096 + f * 64 + gq * 16;
    const float* p1 = a1 + em * 64 + gq * 16;
    const float* p2 = a2 + em * 64 + gq * 16;
    float d1 = 0.f, d2 = 0.f;
#pragma unroll
    for (int q4 = 0; q4 < 4; ++q4) {
      float4 v  = ((const float4*)wp)[q4];
      float4 va = ((const float4*)p1)[q4];
      float4 vb = ((const float4*)p2)[q4];
      float vals[4] = {v.x, v.y, v.z, v.w};
      float aa[4] = {va.x, va.y, va.z, va.w};
      float bb[4] = {vb.x, vb.y, vb.z, vb.w};
#pragma unroll
      for (int u = 0; u < 4; ++u) {
        const int g = gq * 16 + q4 * 4 + u;
        wl[kk][g >> 4][gg * 16 + (g & 15)][ii] = bfu(vals[u]);
        d1 = fmaf(vals[u], aa[u], d1);
        d2 = fmaf(vals[u], bb[u], d2);
      }
    }
    d1 += __shfl_xor(d1, 1); d1 += __shfl_xor(d1, 2);
    d2 += __shfl_xor(d2, 1); d2 += __shfl_xor(d2, 2);
    if (gq == 0) { c1b[f] = d1; c2b[f] = d2; }
  }
  __syncthreads();

  f32x4 acc[4] = {};
#pragma unroll
  for (int kk = 0; kk < 2; ++kk) {
    bf16x8 af = asbf(*(const int4*)&wl[kk][w][lane][0]);
#pragma unroll
    for (int t = 0; t < 4; ++t) {
      bf16x8 bv = asbf(*(const int4*)&xl[kk][t][lane][0]);
      acc[t] = __builtin_amdgcn_mfma_f32_16x16x32_bf16(af, bv, acc[t], 0, 0, 0);
    }
  }
#pragma unroll
  for (int t = 0; t < 4; ++t) {
    const int sl = t >> 1;
    const int gp = (t & 1) * 2 + (c >> 3);
    const int ii = c & 7;
#pragma unroll
    for (int r = 0; r < 4; ++r)
      st[sl * 2048 + w * 512 + (gp * 16 + grp * 4 + r) * 8 + ii] = bfu(acc[t][r]);
  }
  if (w == 0) {                            // s1 + E2 via c1/c2 MFMA rows 0,1
    f32x4 sacc[4] = {};
#pragma unroll
    for (int kk = 0; kk < 2; ++kk) {
      bf16x8 af;
#pragma unroll
      for (int i = 0; i < 8; ++i) {
        const int f = kk * 32 + grp * 8 + i;
        float v = (c == 0) ? c1b[f] : (c == 1) ? c2b[f] : 0.f;
        af[i] = (__bf16)v;
      }
#pragma unroll
      for (int t = 0; t < 4; ++t) {
        bf16x8 bv = asbf(*(const int4*)&xl[kk][t][lane][0]);
        sacc[t] = __builtin_amdgcn_mfma_f32_16x16x32_bf16(af, bv, sacc[t], 0, 0, 0);
      }
    }
    if (grp == 0) {
#pragma unroll
      for (int t = 0; t < 4; ++t) {
        float s2v = sacc[t][1];
        s1[bem * 512 + n0 + t * 16 + c] = sacc[t][0];
        E2[bem * 512 + n0 + t * 16 + c] = make_float2(__expf(s2v), __expf(0.01f * s2v));
      }
    }
  }
  __syncthreads();
  {  // coalesced copy-out: 4096 ush = 2 int4 per thread
    int4* dst = (int4*)(WhF + bem * 32768 + nt * 4096);
    const int4* src = (const int4*)st;
    dst[tid * 2]     = src[tid * 2];
    dst[tid * 2 + 1] = src[tid * 2 + 1];
  }
}

// ---------------- K2: 32 rows/block — two row-fragments share each WhF load --------------
// grid 512, XCD-swizzled; 10 MFMA per 4 loads; 2-deep prefetch (8 int4 in flight).
__global__ void __launch_bounds__(256) k2_attn(const unsigned* __restrict__ Amask,
                                               const ush* __restrict__ WhF,
                                               const float* __restrict__ s1,
                                               const float2* __restrict__ E2,
                                               ush* __restrict__ Hb) {
  const int tid = threadIdx.x, lane = tid & 63, m = tid >> 6;
  const int grp = lane >> 4, col = lane & 15;
  const int blk = blockIdx.x;
  const int xcd = blk & 7, kk2 = blk >> 3;
  const int be = xcd * 4 + (kk2 >> 4), itile = kk2 & 15;   // 16 itiles of 32 rows
  const int b = be >> 2, e = be & 3;
  const int i0 = itile * 32;
  const int bem = be * 4 + m;

  __shared__ unsigned maskw[32][17];
  __shared__ float2 e2l[4][512];

  {  // 32x16 mask words: 2 per thread, coalesced
    const int i_0 = tid, i_1 = tid + 256;
    maskw[i_0 >> 4][i_0 & 15] = Amask[(be * 512 + i0 + (i_0 >> 4)) * 16 + (i_0 & 15)];
    maskw[i_1 >> 4][i_1 & 15] = Amask[(be * 512 + i0 + (i_1 >> 4)) * 16 + (i_1 & 15)];
  }
  {  // stage E2[bem][0..511] into LDS
    const float2* e2g = E2 + bem * 512;
#pragma unroll
    for (int t = 0; t < 8; ++t) e2l[m][t * 64 + lane] = e2g[t * 64 + lane];
  }
  __syncthreads();

  const float s1A = s1[bem * N_ + i0 + col];
  const float s1B = s1[bem * N_ + i0 + 16 + col];
  const float e1pA = __expf(s1A), e1nA = __expf(0.01f * s1A), teA = __expf(-s1A);
  const float e1pB = __expf(s1B), e1nB = __expf(0.01f * s1B), teB = __expf(-s1B);

  const ush* whb = WhF + bem * 32768 + lane * 8;
  f32x4 a0A = {0.f, 0.f, 0.f, 0.f};
  f32x4 a1A = a0A, a2A = a0A, a3A = a0A, sA = a0A;
  f32x4 a0B = a0A, a1B = a0A, a2B = a0A, a3B = a0A, sB = a0A;
  bf16x8 ones;
#pragma unroll
  for (int i = 0; i < 8; ++i) ones[i] = (__bf16)1.0f;

  // 2-deep prefetch: cA = iter s, cB = iter s+1
  int4 cA0 = *(const int4*)(whb + 0);
  int4 cA1 = *(const int4*)(whb + 512);
  int4 cA2 = *(const int4*)(whb + 1024);
  int4 cA3 = *(const int4*)(whb + 1536);
  int4 cB0 = *(const int4*)(whb + 2048);
  int4 cB1 = *(const int4*)(whb + 2560);
  int4 cB2 = *(const int4*)(whb + 3072);
  int4 cB3 = *(const int4*)(whb + 3584);
#pragma unroll
  for (int s = 0; s < 16; ++s) {
    const int noff = ((s + 2) & 15) * 2048;        // wrap: harmless cached re-load
    int4 n0 = *(const int4*)(whb + noff);
    int4 n1 = *(const int4*)(whb + noff + 512);
    int4 n2 = *(const int4*)(whb + noff + 1024);
    int4 n3 = *(const int4*)(whb + noff + 1536);

    const unsigned mbA = maskw[col][s] >> (grp * 8);
    const unsigned mbB = maskw[col + 16][s] >> (grp * 8);
    const float2* ep = &e2l[m][s * 32 + grp * 8];
    bf16x8 afA, afB;
#pragma unroll
    for (int i = 0; i < 8; ++i) {
      float2 q = ep[i];
      float pA = (q.x > teA) ? q.x * e1pA : q.y * e1nA;
      pA = ((mbA >> i) & 1u) ? pA : 0.f;
      afA[i] = (__bf16)pA;
      float pB = (q.x > teB) ? q.x * e1pB : q.y * e1nB;
      pB = ((mbB >> i) & 1u) ? pB : 0.f;
      afB[i] = (__bf16)pB;
    }
    sA  = __builtin_amdgcn_mfma_f32_16x16x32_bf16(afA, ones, sA, 0, 0, 0);
    sB  = __builtin_amdgcn_mfma_f32_16x16x32_bf16(afB, ones, sB, 0, 0, 0);
    a0A = __builtin_amdgcn_mfma_f32_16x16x32_bf16(afA, asbf(cA0), a0A, 0, 0, 0);
    a0B = __builtin_amdgcn_mfma_f32_16x16x32_bf16(afB, asbf(cA0), a0B, 0, 0, 0);
    a1A = __builtin_amdgcn_mfma_f32_16x16x32_bf16(afA, asbf(cA1), a1A, 0, 0, 0);
    a1B = __builtin_amdgcn_mfma_f32_16x16x32_bf16(afB, asbf(cA1), a1B, 0, 0, 0);
    a2A = __builtin_amdgcn_mfma_f32_16x16x32_bf16(afA, asbf(cA2), a2A, 0, 0, 0);
    a2B = __builtin_amdgcn_mfma_f32_16x16x32_bf16(afB, asbf(cA2), a2B, 0, 0, 0);
    a3A = __builtin_amdgcn_mfma_f32_16x16x32_bf16(afA, asbf(cA3), a3A, 0, 0, 0);
    a3B = __builtin_amdgcn_mfma_f32_16x16x32_bf16(afB, asbf(cA3), a3B, 0, 0, 0);
    cA0 = cB0; cA1 = cB1; cA2 = cB2; cA3 = cB3;
    cB0 = n0;  cB1 = n1;  cB2 = n2;  cB3 = n3;
  }

  // epilogue per rowset; sX[r] = row-sum of P for row grp*4+r
  {
    ush* op = Hb + (b * N_ + i0 + grp * 4) * MEG + m * 256 + e * 64 + col;
#pragma unroll
    for (int r = 0; r < 4; ++r) {
      float sv = sA[r];
      float inv = sv > 0.f ? 1.f / sv : 0.f;
      float v0 = a0A[r] * inv; v0 = v0 > 0.f ? v0 : expm1f(v0);
      float v1 = a1A[r] * inv; v1 = v1 > 0.f ? v1 : expm1f(v1);
      float v2 = a2A[r] * inv; v2 = v2 > 0.f ? v2 : expm1f(v2);
      float v3 = a3A[r] * inv; v3 = v3 > 0.f ? v3 : expm1f(v3);
      op[r * MEG + 0]  = bfu(v0);
      op[r * MEG + 16] = bfu(v1);
      op[r * MEG + 32] = bfu(v2);
      op[r * MEG + 48] = bfu(v3);
    }
  }
  {
    ush* op = Hb + (b * N_ + i0 + 16 + grp * 4) * MEG + m * 256 + e * 64 + col;
#pragma unroll
    for (int r = 0; r < 4; ++r) {
      float sv = sB[r];
      float inv = sv > 0.f ? 1.f / sv : 0.f;
      float v0 = a0B[r] * inv; v0 = v0 > 0.f ? v0 : expm1f(v0);
      float v1 = a1B[r] * inv; v1 = v1 > 0.f ? v1 : expm1f(v1);
      float v2 = a2B[r] * inv; v2 = v2 > 0.f ? v2 : expm1f(v2);
      float v3 = a3B[r] * inv; v3 = v3 > 0.f ? v3 : expm1f(v3);
      op[r * MEG + 0]  = bfu(v0);
      op[r * MEG + 16] = bfu(v1);
      op[r * MEG + 32] = bfu(v2);
      op[r * MEG + 48] = bfu(v3);
    }
  }
}

// ---------------- K3: MFMA  R = 0.5*(Hb @ W_emb1^T) + 0.5*X; partials P2R[blk][2][64] -------
__global__ void __launch_bounds__(256) k3_emb(const ush* __restrict__ Hb, const float* __restrict__ W_emb1,
                                              const float* __restrict__ X, float* __restrict__ R,
                                              float* __restrict__ P2R) {
  const int tid = threadIdx.x, lane = tid & 63, w = tid >> 6, c = lane & 15, grp = lane >> 4;
  const int r0 = blockIdx.x * 16;
  const ush* ha = Hb + (r0 + c) * 1024 + grp * 8;
  const float* wbf = W_emb1 + (w * 16 + c) * 1024 + grp * 8;
  f32x4 accA = {}, accB = {};
#pragma unroll 8
  for (int kk = 0; kk < 32; kk += 2) {
    bf16x8 w0 = cvt8(*(const float4*)(wbf + kk * 32),      *(const float4*)(wbf + kk * 32 + 4));
    bf16x8 w1 = cvt8(*(const float4*)(wbf + kk * 32 + 32), *(const float4*)(wbf + kk * 32 + 36));
    accA = __builtin_amdgcn_mfma_f32_16x16x32_bf16(asbf(*(const int4*)(ha + kk * 32)), w0, accA, 0, 0, 0);
    accB = __builtin_amdgcn_mfma_f32_16x16x32_bf16(asbf(*(const int4*)(ha + kk * 32 + 32)), w1, accB, 0, 0, 0);
  }
  f32x4 acc = accA + accB;
  const int col = w * 16 + c;
  float s = 0.f, q = 0.f;
#pragma unroll
  for (int r = 0; r < 4; ++r) {
    int row = r0 + grp * 4 + r;
    float v = 0.5f * acc[r] + 0.5f * X[row * 64 + col];
    R[row * 64 + col] = v;
    s += v; q = fmaf(v, v, q);
  }
  s += __shfl_xor(s, 16); s += __shfl_xor(s, 32);
  q += __shfl_xor(q, 16); q += __shfl_xor(q, 32);
  if (grp == 0) { P2R[blockIdx.x * 128 + col] = s; P2R[blockIdx.x * 128 + 64 + col] = q; }
}

// ---------------- K4: reduce P2R; T = BN(R) @ W2a^T; P2T[blk][2][256] ----
__global__ void __launch_bounds__(256) k4_node1(const float* __restrict__ R, const float* __restrict__ P2R,
                                                const float* __restrict__ W2a,
                                                float* __restrict__ T, float* __restrict__ P2T) {
  const int tid = threadIdx.x, lane = tid & 63, w = tid >> 6, c = lane & 15, grp = lane >> 4;
  const int r0 = blockIdx.x * 16, cb = w * 64;
  __shared__ float muR[64], rsR[64];
  if (tid < 128) {
    const int cc = tid & 63;
    float a = 0.f;
    for (int bk = 0; bk < 256; ++bk) a += P2R[bk * 128 + tid];
    if (tid < 64) muR[cc] = a * (1.f / 4096.f); else rsR[cc] = a;
  }
  __syncthreads();
  if (tid < 64) {
    float m = muR[tid];
    float v = rsR[tid] * (1.f / 4096.f) - m * m;
    rsR[tid] = rsqrtf(v + 1e-5f);
  }
  __syncthreads();

  f32x4 acc[4] = {};
#pragma unroll
  for (int kk = 0; kk < 2; ++kk) {
    const float* rp = R + (r0 + c) * 64 + kk * 32 + grp * 8;
    float4 v0 = *(const float4*)rp;
    float4 v1 = *(const float4*)(rp + 4);
    float vv[8] = {v0.x, v0.y, v0.z, v0.w, v1.x, v1.y, v1.z, v1.w};
    bf16x8 af;
#pragma unroll
    for (int i = 0; i < 8; ++i) {
      int f = kk * 32 + grp * 8 + i;
      af[i] = (__bf16)((vv[i] - muR[f]) * rsR[f]);
    }
#pragma unroll
    for (int ct = 0; ct < 4; ++ct) {
      const float* wp = W2a + (cb + ct * 16 + c) * 64 + kk * 32 + grp * 8;
      bf16x8 bv = cvt8(*(const float4*)wp, *(const float4*)(wp + 4));
      acc[ct] = __builtin_amdgcn_mfma_f32_16x16x32_bf16(af, bv, acc[ct], 0, 0, 0);
    }
  }
#pragma unroll
  for (int ct = 0; ct < 4; ++ct) {
    const int col = cb + ct * 16 + c;
    float s = 0.f, q = 0.f;
#pragma unroll
    for (int r = 0; r < 4; ++r) {
      float v = acc[ct][r];
      T[(r0 + grp * 4 + r) * 256 + col] = v;
      s += v; q = fmaf(v, v, q);
    }
    s += __shfl_xor(s, 16); s += __shfl_xor(s, 32);
    q += __shfl_xor(q, 16); q += __shfl_xor(q, 32);
    if (grp == 0) { P2T[blockIdx.x * 512 + col] = s; P2T[blockIdx.x * 512 + 256 + col] = q; }
  }
}

// ---------------- K5: reduce P2T,P2R; S = BN_R(R) + ELU(BN(T)) @ W2b^T; P2S[blk][2][64] ------
__global__ void __launch_bounds__(256) k5_node2(const float* __restrict__ T, const float* __restrict__ P2T,
                                                const float* __restrict__ W2b,
                                                const float* __restrict__ R, const float* __restrict__ P2R,
                                                float* __restrict__ S, float* __restrict__ P2S) {
  const int tid = threadIdx.x, lane = tid & 63, w = tid >> 6, c = lane & 15, grp = lane >> 4;
  const int r0 = blockIdx.x * 16;
  __shared__ float muT[256], rsT[256], muR[64], rsR[64];
  {
    float s = 0.f, q = 0.f;
    for (int bk = 0; bk < 256; ++bk) {
      s += P2T[bk * 512 + tid];
      q += P2T[bk * 512 + 256 + tid];
    }
    float m = s * (1.f / 4096.f);
    float v = q * (1.f / 4096.f) - m * m;
    muT[tid] = m; rsT[tid] = rsqrtf(v + 1e-5f);
  }
  if (tid < 128) {
    const int cc = tid & 63;
    float a = 0.f;
    for (int bk = 0; bk < 256; ++bk) a += P2R[bk * 128 + tid];
    if (tid < 64) muR[cc] = a * (1.f / 4096.f); else rsR[cc] = a;
  }
  __syncthreads();
  if (tid < 64) {
    float m = muR[tid];
    float v = rsR[tid] * (1.f / 4096.f) - m * m;
    rsR[tid] = rsqrtf(v + 1e-5f);
  }
  __syncthreads();

  f32x4 accA = {}, accB = {};
  const float* wrow = W2b + (w * 16 + c) * 256 + grp * 8;
  const float* trow = T + (r0 + c) * 256 + grp * 8;
#pragma unroll
  for (int kk = 0; kk < 8; ++kk) {
    float4 v0 = *(const float4*)(trow + kk * 32);
    float4 v1 = *(const float4*)(trow + kk * 32 + 4);
    float vv[8] = {v0.x, v0.y, v0.z, v0.w, v1.x, v1.y, v1.z, v1.w};
    bf16x8 af;
#pragma unroll
    for (int i = 0; i < 8; ++i) {
      int u = kk * 32 + grp * 8 + i;
      float t = (vv[i] - muT[u]) * rsT[u];
      t = t > 0.f ? t : expm1f(t);
      af[i] = (__bf16)t;
    }
    bf16x8 bv = cvt8(*(const float4*)(wrow + kk * 32), *(const float4*)(wrow + kk * 32 + 4));
    if (kk & 1) accB = __builtin_amdgcn_mfma_f32_16x16x32_bf16(af, bv, accB, 0, 0, 0);
    else        accA = __builtin_amdgcn_mfma_f32_16x16x32_bf16(af, bv, accA, 0, 0, 0);
  }
  f32x4 acc = accA + accB;
  const int col = w * 16 + c;
  const float mu = muR[col], rsv = rsR[col];
  float s = 0.f, q = 0.f;
#pragma unroll
  for (int r = 0; r < 4; ++r) {
    int row = r0 + grp * 4 + r;
    float v = acc[r] + (R[row * 64 + col] - mu) * rsv;
    S[row * 64 + col] = v;
    s += v; q = fmaf(v, v, q);
  }
  s += __shfl_xor(s, 16); s += __shfl_xor(s, 32);
  q += __shfl_xor(q, 16); q += __shfl_xor(q, 32);
  if (grp == 0) { P2S[blockIdx.x * 128 + col] = s; P2S[blockIdx.x * 128 + 64 + col] = q; }
}

// ---------------- K6: reduce P2S; out = BN(S) ----------------
__global__ void __launch_bounds__(256) k6_bn(const float* __restrict__ S, const float* __restrict__ P2S,
                                             float* __restrict__ out) {
  const int tid = threadIdx.x;
  const int r0 = blockIdx.x * 16;
  __shared__ float muS[64], rsS[64];
  if (tid < 128) {
    const int cc = tid & 63;
    float a = 0.f;
    for (int bk = 0; bk < 256; ++bk) a += P2S[bk * 128 + tid];
    if (tid < 64) muS[cc] = a * (1.f / 4096.f); else rsS[cc] = a;
  }
  __syncthreads();
  if (tid < 64) {
    float m = muS[tid];
    float v = rsS[tid] * (1.f / 4096.f) - m * m;
    rsS[tid] = rsqrtf(v + 1e-5f);
  }
  __syncthreads();
  const int f0 = (tid * 4) & 63;
  float4 v = *(const float4*)(S + r0 * 64 + tid * 4);
  float4 o;
  o.x = (v.x - muS[f0 + 0]) * rsS[f0 + 0];
  o.y = (v.y - muS[f0 + 1]) * rsS[f0 + 1];
  o.z = (v.z - muS[f0 + 2]) * rsS[f0 + 2];
  o.w = (v.w - muS[f0 + 3]) * rsS[f0 + 3];
  *(float4*)(out + r0 * 64 + tid * 4) = o;
}

extern "C" void kernel_launch(void* const* d_in, const int* in_sizes, int n_in,
                              void* d_out, int out_size, void* d_ws, size_t ws_size,
                              hipStream_t stream) {
  const int*   A      = (const int*)d_in[0];
  const float* X      = (const float*)d_in[1];
  const float* Ws     = (const float*)d_in[2];
  const float* a1     = (const float*)d_in[3];
  const float* a2     = (const float*)d_in[4];
  const float* W_emb1 = (const float*)d_in[5];
  const float* W2a    = (const float*)d_in[6];
  const float* W2b    = (const float*)d_in[7];
  float* out = (float*)d_out;

  float* ws = (float*)d_ws;
  ush*   Hb    = (ush*)d_ws;                 // [4096][1024] bf16   (2,097,152 fl)
  ush*   WhF   = (ush*)(ws + 2097152);       // [128][16][4][64][8] bf16 (2,097,152 fl)
  float* s1    = ws + 4194304;               // 65,536
  float2* E2   = (float2*)(ws + 4259840);    // [128][512] float2 = 131,072 fl
  float* R     = ws + 4612096;               // 262,144
  float* T     = ws + 4874240;               // 1,048,576
  float* S     = ws + 5922816;               // 262,144
  float* P2R   = ws + 6184960;               // 32,768  [256][2][64]
  float* P2T   = ws + 6217728;               // 131,072 [256][2][256]
  float* P2S   = ws + 6348800;               // 32,768  [256][2][64]  (end ~25.5 MB)
  // Amask [32 be][512 i][16 c] uint aliases R (k1 writes, k2 reads, k3 overwrites R later).
  unsigned* Amask = (unsigned*)R;

  k1_wh<<<1024, 256, 0, stream>>>(X, Ws, a1, a2, A, WhF, s1, E2, Amask);
  k2_attn<<<512, 256, 0, stream>>>(Amask, WhF, s1, E2, Hb);
  k3_emb<<<256, 256, 0, stream>>>(Hb, W_emb1, X, R, P2R);
  k4_node1<<<256, 256, 0, stream>>>(R, P2R, W2a, T, P2T);
  k5_node2<<<256, 256, 0, stream>>>(T, P2T, W2b, R, P2R, S, P2S);
  k6_bn<<<256, 256, 0, stream>>>(S, P2S, out);
}

// Round 14
// 83.118 us; speedup vs baseline: 1.1661x; 1.1661x over previous
//
#include <hip/hip_runtime.h>
#include <math.h>

#define B_   8
#define N_   512
#define F_   64
#define G_   64
#define M_   4
#define E_   4
#define MEG  1024

typedef __attribute__((ext_vector_type(8))) __bf16 bf16x8;
typedef __attribute__((ext_vector_type(4))) float f32x4;
typedef unsigned short ush;

static __device__ __forceinline__ ush bfu(float x) { __bf16 h = (__bf16)x; return __builtin_bit_cast(ush, h); }
static __device__ __forceinline__ bf16x8 asbf(int4 v) { return __builtin_bit_cast(bf16x8, v); }
static __device__ __forceinline__ bf16x8 cvt8(float4 a, float4 b) {
  bf16x8 r;
  r[0] = (__bf16)a.x; r[1] = (__bf16)a.y; r[2] = (__bf16)a.z; r[3] = (__bf16)a.w;
  r[4] = (__bf16)b.x; r[5] = (__bf16)b.y; r[6] = (__bf16)b.z; r[7] = (__bf16)b.w;
  return r;
}

// ---------------- K1 (self-staged): MFMA Wh -> WhF fragment-major + s1/E2 + A->bitmask ------
__global__ void __launch_bounds__(256) k1_wh(const float* __restrict__ X, const float* __restrict__ Ws,
                                             const float* __restrict__ a1, const float* __restrict__ a2,
                                             const int* __restrict__ A,
                                             ush* __restrict__ WhF, float* __restrict__ s1,
                                             float2* __restrict__ E2, unsigned* __restrict__ Amask) {
  const int tid = threadIdx.x, lane = tid & 63, w = tid >> 6, c = lane & 15, grp = lane >> 4;
  const int blk = blockIdx.x, nt = blk & 7, em = (blk >> 3) & 15, b = blk >> 7;
  const int n0 = nt * 64, bem = b * 16 + em;

  __shared__ __align__(16) ush xl[2][4][64][8];   // [kk][t][lane][i]  8KB  (X fragments)
  __shared__ __align__(16) ush wl[2][4][64][8];   // [kk][w][lane][i]  8KB  (WsT fragments)
  __shared__ float c1b[64], c2b[64];
  __shared__ __align__(16) ush st[4096];          // WhF store staging 8KB

  // A -> bitmask: one 32-bit word per thread; 128B contiguous read.
  {
    const int w2 = blk * 256 + tid;               // [be][i][cword]
    const int* ap = A + (w2 >> 4) * 512 + (w2 & 15) * 32;
    unsigned bits = 0;
#pragma unroll
    for (int kq = 0; kq < 32; kq += 4) {
      int4 v = *(const int4*)(ap + kq);
      bits |= (v.x > 0 ? 1u : 0u) << kq;
      bits |= (v.y > 0 ? 1u : 0u) << (kq + 1);
      bits |= (v.z > 0 ? 1u : 0u) << (kq + 2);
      bits |= (v.w > 0 ? 1u : 0u) << (kq + 3);
    }
    Amask[w2] = bits;
  }

  // stage X rows [n0, n0+64) -> fragment-major bf16
  {
    const int row = tid >> 2, cg = tid & 3;
    const int t = row >> 4, cc = row & 15;
    const float* xp = X + (b * 512 + n0 + row) * 64 + cg * 16;
#pragma unroll
    for (int q4 = 0; q4 < 4; ++q4) {
      float4 v = ((const float4*)xp)[q4];
      float vals[4] = {v.x, v.y, v.z, v.w};
#pragma unroll
      for (int u = 0; u < 4; ++u) {
        const int f = cg * 16 + q4 * 4 + u;
        xl[f >> 5][t][((f >> 3) & 3) * 16 + cc][f & 7] = bfu(vals[u]);
      }
    }
  }
  // stage Ws[em] transposed fragment-major + c1/c2 partial dots
  {
    const int f = tid >> 2, gq = tid & 3;
    const int kk = f >> 5, gg = (f >> 3) & 3, ii = f & 7;
    const float* wp = Ws + em * 4096 + f * 64 + gq * 16;
    const float* p1 = a1 + em * 64 + gq * 16;
    const float* p2 = a2 + em * 64 + gq * 16;
    float d1 = 0.f, d2 = 0.f;
#pragma unroll
    for (int q4 = 0; q4 < 4; ++q4) {
      float4 v  = ((const float4*)wp)[q4];
      float4 va = ((const float4*)p1)[q4];
      float4 vb = ((const float4*)p2)[q4];
      float vals[4] = {v.x, v.y, v.z, v.w};
      float aa[4] = {va.x, va.y, va.z, va.w};
      float bb[4] = {vb.x, vb.y, vb.z, vb.w};
#pragma unroll
      for (int u = 0; u < 4; ++u) {
        const int g = gq * 16 + q4 * 4 + u;
        wl[kk][g >> 4][gg * 16 + (g & 15)][ii] = bfu(vals[u]);
        d1 = fmaf(vals[u], aa[u], d1);
        d2 = fmaf(vals[u], bb[u], d2);
      }
    }
    d1 += __shfl_xor(d1, 1); d1 += __shfl_xor(d1, 2);
    d2 += __shfl_xor(d2, 1); d2 += __shfl_xor(d2, 2);
    if (gq == 0) { c1b[f] = d1; c2b[f] = d2; }
  }
  __syncthreads();

  f32x4 acc[4] = {};
#pragma unroll
  for (int kk = 0; kk < 2; ++kk) {
    bf16x8 af = asbf(*(const int4*)&wl[kk][w][lane][0]);
#pragma unroll
    for (int t = 0; t < 4; ++t) {
      bf16x8 bv = asbf(*(const int4*)&xl[kk][t][lane][0]);
      acc[t] = __builtin_amdgcn_mfma_f32_16x16x32_bf16(af, bv, acc[t], 0, 0, 0);
    }
  }
#pragma unroll
  for (int t = 0; t < 4; ++t) {
    const int sl = t >> 1;
    const int gp = (t & 1) * 2 + (c >> 3);
    const int ii = c & 7;
#pragma unroll
    for (int r = 0; r < 4; ++r)
      st[sl * 2048 + w * 512 + (gp * 16 + grp * 4 + r) * 8 + ii] = bfu(acc[t][r]);
  }
  if (w == 0) {                            // s1 + E2 via c1/c2 MFMA rows 0,1
    f32x4 sacc[4] = {};
#pragma unroll
    for (int kk = 0; kk < 2; ++kk) {
      bf16x8 af;
#pragma unroll
      for (int i = 0; i < 8; ++i) {
        const int f = kk * 32 + grp * 8 + i;
        float v = (c == 0) ? c1b[f] : (c == 1) ? c2b[f] : 0.f;
        af[i] = (__bf16)v;
      }
#pragma unroll
      for (int t = 0; t < 4; ++t) {
        bf16x8 bv = asbf(*(const int4*)&xl[kk][t][lane][0]);
        sacc[t] = __builtin_amdgcn_mfma_f32_16x16x32_bf16(af, bv, sacc[t], 0, 0, 0);
      }
    }
    if (grp == 0) {
#pragma unroll
      for (int t = 0; t < 4; ++t) {
        float s2v = sacc[t][1];
        s1[bem * 512 + n0 + t * 16 + c] = sacc[t][0];
        E2[bem * 512 + n0 + t * 16 + c] = make_float2(__expf(s2v), __expf(0.01f * s2v));
      }
    }
  }
  __syncthreads();
  {  // coalesced copy-out: 4096 ush = 2 int4 per thread
    int4* dst = (int4*)(WhF + bem * 32768 + nt * 4096);
    const int4* src = (const int4*)st;
    dst[tid * 2]     = src[tid * 2];
    dst[tid * 2 + 1] = src[tid * 2 + 1];
  }
}

// ---------------- K2: factorized softmax + coalesced MFMA PV + ELU -> Hb bf16 (R11) -------
__global__ void __launch_bounds__(256) k2_attn(const unsigned* __restrict__ Amask,
                                               const ush* __restrict__ WhF,
                                               const float* __restrict__ s1,
                                               const float2* __restrict__ E2,
                                               ush* __restrict__ Hb) {
  const int tid = threadIdx.x, lane = tid & 63, m = tid >> 6;
  const int grp = lane >> 4, col = lane & 15;
  const int blk = blockIdx.x;
  const int xcd = blk & 7, kk2 = blk >> 3;
  const int be = xcd * 4 + (kk2 >> 5), itile = kk2 & 31;
  const int b = be >> 2, e = be & 3;
  const int i0 = itile * 16;
  const int bem = be * 4 + m;

  __shared__ unsigned maskw[16][17];
  __shared__ float2 e2l[4][512];

  {
    const int row = tid >> 4, cc = tid & 15;
    maskw[row][cc] = Amask[(be * 512 + i0 + row) * 16 + cc];
  }
  {
    const float2* e2g = E2 + bem * 512;
#pragma unroll
    for (int t = 0; t < 8; ++t) e2l[m][t * 64 + lane] = e2g[t * 64 + lane];
  }
  __syncthreads();

  const float s1row = s1[bem * N_ + i0 + col];
  const float e1p = __expf(s1row);
  const float e1n = __expf(0.01f * s1row);
  const float te  = __expf(-s1row);

  const ush* whb = WhF + bem * 32768 + lane * 8;
  f32x4 acc0 = {0.f, 0.f, 0.f, 0.f};
  f32x4 acc1 = acc0, acc2 = acc0, acc3 = acc0, accs = acc0;
  bf16x8 ones;
#pragma unroll
  for (int i = 0; i < 8; ++i) ones[i] = (__bf16)1.0f;

  int4 c0 = *(const int4*)(whb + 0);
  int4 c1 = *(const int4*)(whb + 512);
  int4 c2 = *(const int4*)(whb + 1024);
  int4 c3 = *(const int4*)(whb + 1536);
#pragma unroll 4
  for (int s = 0; s < 16; ++s) {
    const int noff = ((s + 1) & 15) * 2048;
    int4 n0 = *(const int4*)(whb + noff);
    int4 n1 = *(const int4*)(whb + noff + 512);
    int4 n2 = *(const int4*)(whb + noff + 1024);
    int4 n3 = *(const int4*)(whb + noff + 1536);

    unsigned mb = maskw[col][s] >> (grp * 8);
    const float2* ep = &e2l[m][s * 32 + grp * 8];
    bf16x8 af;
#pragma unroll
    for (int i = 0; i < 8; ++i) {
      float2 q = ep[i];
      float p = (q.x > te) ? q.x * e1p : q.y * e1n;
      p = ((mb >> i) & 1u) ? p : 0.f;
      af[i] = (__bf16)p;
    }
    accs = __builtin_amdgcn_mfma_f32_16x16x32_bf16(af, ones, accs, 0, 0, 0);
    acc0 = __builtin_amdgcn_mfma_f32_16x16x32_bf16(af, asbf(c0), acc0, 0, 0, 0);
    acc1 = __builtin_amdgcn_mfma_f32_16x16x32_bf16(af, asbf(c1), acc1, 0, 0, 0);
    acc2 = __builtin_amdgcn_mfma_f32_16x16x32_bf16(af, asbf(c2), acc2, 0, 0, 0);
    acc3 = __builtin_amdgcn_mfma_f32_16x16x32_bf16(af, asbf(c3), acc3, 0, 0, 0);
    c0 = n0; c1 = n1; c2 = n2; c3 = n3;
  }

  ush* op = Hb + (b * N_ + i0 + grp * 4) * MEG + m * 256 + e * 64 + col;
#pragma unroll
  for (int r = 0; r < 4; ++r) {
    float sv2 = accs[r];
    float inv = sv2 > 0.f ? 1.f / sv2 : 0.f;
    float v0 = acc0[r] * inv; v0 = v0 > 0.f ? v0 : expm1f(v0);
    float v1 = acc1[r] * inv; v1 = v1 > 0.f ? v1 : expm1f(v1);
    float v2 = acc2[r] * inv; v2 = v2 > 0.f ? v2 : expm1f(v2);
    float v3 = acc3[r] * inv; v3 = v3 > 0.f ? v3 : expm1f(v3);
    op[r * MEG + 0]  = bfu(v0);
    op[r * MEG + 16] = bfu(v1);
    op[r * MEG + 32] = bfu(v2);
    op[r * MEG + 48] = bfu(v3);
  }
}

// ---------------- K3: 8-wave K-split MFMA  R = 0.5*(Hb @ W_emb1^T) + 0.5*X ------------------
__global__ void __launch_bounds__(512) k3_emb(const ush* __restrict__ Hb, const float* __restrict__ W_emb1,
                                              const float* __restrict__ X, float* __restrict__ R,
                                              float* __restrict__ P2R) {
  const int tid = threadIdx.x, lane = tid & 63, w8 = tid >> 6, c = lane & 15, grp = lane >> 4;
  const int wcol = w8 & 3, khalf = w8 >> 2;
  const int r0 = blockIdx.x * 16;
  __shared__ float part[4][64][4];

  const ush* ha = Hb + (r0 + c) * 1024 + khalf * 512 + grp * 8;
  const float* wbf = W_emb1 + (wcol * 16 + c) * 1024 + khalf * 512 + grp * 8;
  f32x4 accA = {}, accB = {};
#pragma unroll 8
  for (int kk = 0; kk < 16; kk += 2) {
    bf16x8 w0 = cvt8(*(const float4*)(wbf + kk * 32),      *(const float4*)(wbf + kk * 32 + 4));
    bf16x8 w1 = cvt8(*(const float4*)(wbf + kk * 32 + 32), *(const float4*)(wbf + kk * 32 + 36));
    accA = __builtin_amdgcn_mfma_f32_16x16x32_bf16(asbf(*(const int4*)(ha + kk * 32)), w0, accA, 0, 0, 0);
    accB = __builtin_amdgcn_mfma_f32_16x16x32_bf16(asbf(*(const int4*)(ha + kk * 32 + 32)), w1, accB, 0, 0, 0);
  }
  f32x4 acc = accA + accB;
  if (khalf == 1) {
#pragma unroll
    for (int r = 0; r < 4; ++r) part[wcol][lane][r] = acc[r];
  }
  __syncthreads();
  if (khalf == 0) {
    const int col = wcol * 16 + c;
    float s = 0.f, q = 0.f;
#pragma unroll
    for (int r = 0; r < 4; ++r) {
      int row = r0 + grp * 4 + r;
      float v = 0.5f * (acc[r] + part[wcol][lane][r]) + 0.5f * X[row * 64 + col];
      R[row * 64 + col] = v;
      s += v; q = fmaf(v, v, q);
    }
    s += __shfl_xor(s, 16); s += __shfl_xor(s, 32);
    q += __shfl_xor(q, 16); q += __shfl_xor(q, 32);
    if (grp == 0) { P2R[blockIdx.x * 128 + col] = s; P2R[blockIdx.x * 128 + 64 + col] = q; }
  }
}

// ---------------- K4: 8-wave; parallel stats; T = BN(R) @ W2a^T; P2T[blk][2][256] ----
__global__ void __launch_bounds__(512) k4_node1(const float* __restrict__ R, const float* __restrict__ P2R,
                                                const float* __restrict__ W2a,
                                                float* __restrict__ T, float* __restrict__ P2T) {
  const int tid = threadIdx.x, lane = tid & 63, w8 = tid >> 6, c = lane & 15, grp = lane >> 4;
  const int r0 = blockIdx.x * 16, cb = w8 * 32;
  __shared__ float muR[64], rsR[64];
  __shared__ float red8[8][64];
  {  // sum: 64 cols x 8 chunks of 32
    const int cc = tid & 63, ch = tid >> 6;
    float a = 0.f;
    for (int bk = ch * 32; bk < ch * 32 + 32; ++bk) a += P2R[bk * 128 + cc];
    red8[ch][cc] = a;
  }
  __syncthreads();
  if (tid < 64) {
    float a = 0.f;
#pragma unroll
    for (int ch = 0; ch < 8; ++ch) a += red8[ch][tid];
    muR[tid] = a * (1.f / 4096.f);
  }
  __syncthreads();
  {  // sumsq
    const int cc = tid & 63, ch = tid >> 6;
    float a = 0.f;
    for (int bk = ch * 32; bk < ch * 32 + 32; ++bk) a += P2R[bk * 128 + 64 + cc];
    red8[ch][cc] = a;
  }
  __syncthreads();
  if (tid < 64) {
    float a = 0.f;
#pragma unroll
    for (int ch = 0; ch < 8; ++ch) a += red8[ch][tid];
    float m = muR[tid];
    rsR[tid] = rsqrtf(a * (1.f / 4096.f) - m * m + 1e-5f);
  }
  __syncthreads();

  f32x4 acc[2] = {};
#pragma unroll
  for (int kk = 0; kk < 2; ++kk) {
    const float* rp = R + (r0 + c) * 64 + kk * 32 + grp * 8;
    float4 v0 = *(const float4*)rp;
    float4 v1 = *(const float4*)(rp + 4);
    float vv[8] = {v0.x, v0.y, v0.z, v0.w, v1.x, v1.y, v1.z, v1.w};
    bf16x8 af;
#pragma unroll
    for (int i = 0; i < 8; ++i) {
      int f = kk * 32 + grp * 8 + i;
      af[i] = (__bf16)((vv[i] - muR[f]) * rsR[f]);
    }
#pragma unroll
    for (int ct = 0; ct < 2; ++ct) {
      const float* wp = W2a + (cb + ct * 16 + c) * 64 + kk * 32 + grp * 8;
      bf16x8 bv = cvt8(*(const float4*)wp, *(const float4*)(wp + 4));
      acc[ct] = __builtin_amdgcn_mfma_f32_16x16x32_bf16(af, bv, acc[ct], 0, 0, 0);
    }
  }
#pragma unroll
  for (int ct = 0; ct < 2; ++ct) {
    const int col = cb + ct * 16 + c;
    float s = 0.f, q = 0.f;
#pragma unroll
    for (int r = 0; r < 4; ++r) {
      float v = acc[ct][r];
      T[(r0 + grp * 4 + r) * 256 + col] = v;
      s += v; q = fmaf(v, v, q);
    }
    s += __shfl_xor(s, 16); s += __shfl_xor(s, 32);
    q += __shfl_xor(q, 16); q += __shfl_xor(q, 32);
    if (grp == 0) { P2T[blockIdx.x * 512 + col] = s; P2T[blockIdx.x * 512 + 256 + col] = q; }
  }
}

// ---------------- K5: 8-wave K-split; parallel stats; S = BN_R(R) + ELU(BN(T)) @ W2b^T ------
__global__ void __launch_bounds__(512) k5_node2(const float* __restrict__ T, const float* __restrict__ P2T,
                                                const float* __restrict__ W2b,
                                                const float* __restrict__ R, const float* __restrict__ P2R,
                                                float* __restrict__ S, float* __restrict__ P2S) {
  const int tid = threadIdx.x, lane = tid & 63, w8 = tid >> 6, c = lane & 15, grp = lane >> 4;
  const int wcol = w8 & 3, khalf = w8 >> 2;
  const int r0 = blockIdx.x * 16;
  __shared__ float muT[256], rsT[256], muR[64], rsR[64];
  __shared__ float redT[2][256];
  __shared__ float red8[8][64];
  __shared__ float part[4][64][4];
  {  // muT sum: 256 cols x 2 chunks of 128
    const int cc = tid & 255, ch = tid >> 8;
    float s = 0.f;
    for (int bk = ch * 128; bk < ch * 128 + 128; ++bk) s += P2T[bk * 512 + cc];
    redT[ch][cc] = s;
  }
  __syncthreads();
  if (tid < 256) muT[tid] = (redT[0][tid] + redT[1][tid]) * (1.f / 4096.f);
  __syncthreads();
  {  // muT sumsq
    const int cc = tid & 255, ch = tid >> 8;
    float q = 0.f;
    for (int bk = ch * 128; bk < ch * 128 + 128; ++bk) q += P2T[bk * 512 + 256 + cc];
    redT[ch][cc] = q;
  }
  {  // muR sum (independent of redT): 64 cols x 8 chunks of 32
    const int cc = tid & 63, ch = tid >> 6;
    float s = 0.f;
    for (int bk = ch * 32; bk < ch * 32 + 32; ++bk) s += P2R[bk * 128 + cc];
    red8[ch][cc] = s;
  }
  __syncthreads();
  if (tid < 256) {
    float m = muT[tid];
    rsT[tid] = rsqrtf((redT[0][tid] + redT[1][tid]) * (1.f / 4096.f) - m * m + 1e-5f);
  }
  if (tid >= 256 && tid < 320) {
    const int cc = tid - 256;
    float a = 0.f;
#pragma unroll
    for (int ch = 0; ch < 8; ++ch) a += red8[ch][cc];
    muR[cc] = a * (1.f / 4096.f);
  }
  __syncthreads();
  {  // muR sumsq
    const int cc = tid & 63, ch = tid >> 6;
    float q = 0.f;
    for (int bk = ch * 32; bk < ch * 32 + 32; ++bk) q += P2R[bk * 128 + 64 + cc];
    red8[ch][cc] = q;
  }
  __syncthreads();
  if (tid < 64) {
    float a = 0.f;
#pragma unroll
    for (int ch = 0; ch < 8; ++ch) a += red8[ch][tid];
    float m = muR[tid];
    rsR[tid] = rsqrtf(a * (1.f / 4096.f) - m * m + 1e-5f);
  }
  __syncthreads();

  f32x4 accA = {}, accB = {};
  const float* wrow = W2b + (wcol * 16 + c) * 256 + grp * 8;
  const float* trow = T + (r0 + c) * 256 + grp * 8;
#pragma unroll
  for (int kk = khalf * 4; kk < khalf * 4 + 4; ++kk) {
    float4 v0 = *(const float4*)(trow + kk * 32);
    float4 v1 = *(const float4*)(trow + kk * 32 + 4);
    float vv[8] = {v0.x, v0.y, v0.z, v0.w, v1.x, v1.y, v1.z, v1.w};
    bf16x8 af;
#pragma unroll
    for (int i = 0; i < 8; ++i) {
      int u = kk * 32 + grp * 8 + i;
      float t = (vv[i] - muT[u]) * rsT[u];
      t = t > 0.f ? t : expm1f(t);
      af[i] = (__bf16)t;
    }
    bf16x8 bv = cvt8(*(const float4*)(wrow + kk * 32), *(const float4*)(wrow + kk * 32 + 4));
    if (kk & 1) accB = __builtin_amdgcn_mfma_f32_16x16x32_bf16(af, bv, accB, 0, 0, 0);
    else        accA = __builtin_amdgcn_mfma_f32_16x16x32_bf16(af, bv, accA, 0, 0, 0);
  }
  f32x4 acc = accA + accB;
  if (khalf == 1) {
#pragma unroll
    for (int r = 0; r < 4; ++r) part[wcol][lane][r] = acc[r];
  }
  __syncthreads();
  if (khalf == 0) {
    const int col = wcol * 16 + c;
    const float mu = muR[col], rsv = rsR[col];
    float s = 0.f, q = 0.f;
#pragma unroll
    for (int r = 0; r < 4; ++r) {
      int row = r0 + grp * 4 + r;
      float v = acc[r] + part[wcol][lane][r] + (R[row * 64 + col] - mu) * rsv;
      S[row * 64 + col] = v;
      s += v; q = fmaf(v, v, q);
    }
    s += __shfl_xor(s, 16); s += __shfl_xor(s, 32);
    q += __shfl_xor(q, 16); q += __shfl_xor(q, 32);
    if (grp == 0) { P2S[blockIdx.x * 128 + col] = s; P2S[blockIdx.x * 128 + 64 + col] = q; }
  }
}

// ---------------- K6: parallel stats; out = BN(S) ----------------
__global__ void __launch_bounds__(256) k6_bn(const float* __restrict__ S, const float* __restrict__ P2S,
                                             float* __restrict__ out) {
  const int tid = threadIdx.x;
  const int r0 = blockIdx.x * 16;
  __shared__ float muS[64], rsS[64];
  __shared__ float red4[4][64];
  {  // sum: 64 cols x 4 chunks of 64
    const int cc = tid & 63, ch = tid >> 6;
    float a = 0.f;
    for (int bk = ch * 64; bk < ch * 64 + 64; ++bk) a += P2S[bk * 128 + cc];
    red4[ch][cc] = a;
  }
  __syncthreads();
  if (tid < 64) muS[tid] = (red4[0][tid] + red4[1][tid] + red4[2][tid] + red4[3][tid]) * (1.f / 4096.f);
  __syncthreads();
  {  // sumsq
    const int cc = tid & 63, ch = tid >> 6;
    float a = 0.f;
    for (int bk = ch * 64; bk < ch * 64 + 64; ++bk) a += P2S[bk * 128 + 64 + cc];
    red4[ch][cc] = a;
  }
  __syncthreads();
  if (tid < 64) {
    float q = red4[0][tid] + red4[1][tid] + red4[2][tid] + red4[3][tid];
    float m = muS[tid];
    rsS[tid] = rsqrtf(q * (1.f / 4096.f) - m * m + 1e-5f);
  }
  __syncthreads();
  const int f0 = (tid * 4) & 63;
  float4 v = *(const float4*)(S + r0 * 64 + tid * 4);
  float4 o;
  o.x = (v.x - muS[f0 + 0]) * rsS[f0 + 0];
  o.y = (v.y - muS[f0 + 1]) * rsS[f0 + 1];
  o.z = (v.z - muS[f0 + 2]) * rsS[f0 + 2];
  o.w = (v.w - muS[f0 + 3]) * rsS[f0 + 3];
  *(float4*)(out + r0 * 64 + tid * 4) = o;
}

extern "C" void kernel_launch(void* const* d_in, const int* in_sizes, int n_in,
                              void* d_out, int out_size, void* d_ws, size_t ws_size,
                              hipStream_t stream) {
  const int*   A      = (const int*)d_in[0];
  const float* X      = (const float*)d_in[1];
  const float* Ws     = (const float*)d_in[2];
  const float* a1     = (const float*)d_in[3];
  const float* a2     = (const float*)d_in[4];
  const float* W_emb1 = (const float*)d_in[5];
  const float* W2a    = (const float*)d_in[6];
  const float* W2b    = (const float*)d_in[7];
  float* out = (float*)d_out;

  float* ws = (float*)d_ws;
  ush*   Hb    = (ush*)d_ws;                 // [4096][1024] bf16   (2,097,152 fl)
  ush*   WhF   = (ush*)(ws + 2097152);       // [128][16][4][64][8] bf16 (2,097,152 fl)
  float* s1    = ws + 4194304;               // 65,536
  float2* E2   = (float2*)(ws + 4259840);    // [128][512] float2 = 131,072 fl
  float* R     = ws + 4612096;               // 262,144
  float* T     = ws + 4874240;               // 1,048,576
  float* S     = ws + 5922816;               // 262,144
  float* P2R   = ws + 6184960;               // 32,768  [256][2][64]
  float* P2T   = ws + 6217728;               // 131,072 [256][2][256]
  float* P2S   = ws + 6348800;               // 32,768  [256][2][64]  (end ~25.5 MB)
  // Amask [32 be][512 i][16 c] uint aliases R (k1 writes, k2 reads, k3 overwrites R later).
  unsigned* Amask = (unsigned*)R;

  k1_wh<<<1024, 256, 0, stream>>>(X, Ws, a1, a2, A, WhF, s1, E2, Amask);
  k2_attn<<<1024, 256, 0, stream>>>(Amask, WhF, s1, E2, Hb);
  k3_emb<<<256, 512, 0, stream>>>(Hb, W_emb1, X, R, P2R);
  k4_node1<<<256, 512, 0, stream>>>(R, P2R, W2a, T, P2T);
  k5_node2<<<256, 512, 0, stream>>>(T, P2T, W2b, R, P2R, S, P2S);
  k6_bn<<<256, 256, 0, stream>>>(S, P2S, out);
}